// Round 3
// baseline (364.171 us; speedup 1.0000x reference)
//
#include <hip/hip_runtime.h>
#include <math.h>

// PositionFeaturizer on MI355X — round 2:
//  * qk stored fp8 e4m3 (HW cvt): edge gather 512->256 MB logical
//  * edge_kernel: 8 edges/wave, lane=(edge,head), 64 dims in-lane, no shuffles
//  * gemm1 epilogue: fast gelu via sigmoid form (exp+rcp), no tanhf
//  * GEMMs keep global_load_lds width-16 staging (m97 structure)

typedef unsigned short u16;
typedef __attribute__((ext_vector_type(8))) short bf16x8;   // 8 bf16 in 4 VGPRs
typedef __attribute__((ext_vector_type(4))) float f32x4;
typedef __attribute__((ext_vector_type(2))) float f32x2;

constexpr int N_NODES = 16384;
constexpr int E_EDGES = 262144;
constexpr int D = 512;
constexpr int KIN = 544;    // 536 padded to multiple of 32

// workspace layout (bytes)
constexpr size_t OFF_ZATT = 0;                       // 16384*512*2  = 16,777,216
constexpr size_t OFF_ZCAT = 16777216;                // 16384*544*2  = 17,825,792
constexpr size_t OFF_WQK  = 34603008;                // 1024*512*2   = 1,048,576
constexpr size_t OFF_BQK  = 35651584;                // 1024*4       = 4,096
constexpr size_t OFF_WIN  = 35655680;                // 1024*544*2   = 1,114,112
constexpr size_t OFF_WOUT = 36769792;                // 512*1024*2   = 1,048,576
constexpr size_t OFF_QK   = 37818368;                // 16384*1024*1 = 16,777,216 (fp8)
constexpr size_t OFF_DEN  = 104927232;               // 16384*8*4    = 524,288
constexpr size_t OFF_WSUM = 105451520;               // 524,288
constexpr size_t OFF_WSP  = 105975808;               // 16384*8*3*4  = 1,572,864
constexpr size_t OFF_HBF  = 107548672;               // 16384*1024*2 = 33,554,432

static __device__ __forceinline__ u16 f2bf(float f) {
  union { float f; unsigned int u; } v; v.f = f;
  unsigned int u = v.u;
  u = u + 0x7FFFu + ((u >> 16) & 1u);   // RNE
  return (u16)(u >> 16);
}
// async global->LDS, 16 B per lane; LDS dest = wave-uniform base + lane*16
static __device__ __forceinline__ void gload16(const u16* g, u16* l) {
  __builtin_amdgcn_global_load_lds(
      (const __attribute__((address_space(1))) unsigned int*)g,
      (__attribute__((address_space(3))) unsigned int*)l, 16, 0, 0);
}

// ---------------------------------------------------------------- weights cast
__global__ __launch_bounds__(256) void prep_weights(
    const float* __restrict__ Wq, const float* __restrict__ Wk,
    const float* __restrict__ bq, const float* __restrict__ bk,
    const float* __restrict__ W_in, const float* __restrict__ W_out,
    u16* __restrict__ wqk, float* __restrict__ bqk,
    u16* __restrict__ win, u16* __restrict__ wout)
{
  const int gid = blockIdx.x * 256 + threadIdx.x;
  if (gid < 512 * 1024) {
    wqk[gid]  = f2bf(gid < 512 * 512 ? Wq[gid] : Wk[gid - 512 * 512]);
    wout[gid] = f2bf(W_out[gid]);
  }
  if (gid < 1024 * 544) {
    const int r = gid / 544, c = gid - r * 544;
    win[gid] = f2bf(c < 536 ? W_in[r * 536 + c] : 0.f);
  }
  if (gid < 1024) bqk[gid] = gid < 512 ? bq[gid] : bk[gid - 512];
}

// ---------------------------------------------------------------- dual layernorm
__global__ __launch_bounds__(256) void ln_kernel(
    const float* __restrict__ x,
    const float* __restrict__ g1, const float* __restrict__ b1,
    const float* __restrict__ g2, const float* __restrict__ b2,
    u16* __restrict__ zatt, u16* __restrict__ zcat)
{
  const int row = blockIdx.x;
  const int t = threadIdx.x;
  const float2 v = *(const float2*)(x + (size_t)row * D + t * 2);
  float s = v.x + v.y;
  float s2 = v.x * v.x + v.y * v.y;
#pragma unroll
  for (int m = 1; m < 64; m <<= 1) {
    s  += __shfl_xor(s, m, 64);
    s2 += __shfl_xor(s2, m, 64);
  }
  __shared__ float red[8];
  const int wv = t >> 6;
  if ((t & 63) == 0) { red[wv] = s; red[4 + wv] = s2; }
  __syncthreads();
  s  = red[0] + red[1] + red[2] + red[3];
  s2 = red[4] + red[5] + red[6] + red[7];
  const float mu = s * (1.f / D);
  const float var = s2 * (1.f / D) - mu * mu;
  const float rs = rsqrtf(var + 1e-5f);
  const int c0 = t * 2;
  const float n0 = (v.x - mu) * rs, n1 = (v.y - mu) * rs;
  zatt[(size_t)row * D + c0]       = f2bf(n0 * g1[c0] + b1[c0]);
  zatt[(size_t)row * D + c0 + 1]   = f2bf(n1 * g1[c0 + 1] + b1[c0 + 1]);
  zcat[(size_t)row * KIN + c0]     = f2bf(n0 * g2[c0] + b2[c0]);
  zcat[(size_t)row * KIN + c0 + 1] = f2bf(n1 * g2[c0 + 1] + b2[c0 + 1]);
  if (t < 32) zcat[(size_t)row * KIN + D + t] = 0;   // feat slot + K-pad zeroed
}

// ---------------------------------------------------------------- NT GEMM (bf16 MFMA)
// C[M,Nn] = A[M,K] @ B[Nn,K]^T + bias.
// EPI: 1=fast-gelu->bf16 out; 2=+resid f32 out; 4=fp8 e4m3 out.
template <int EPI>
__global__ __launch_bounds__(256) void gemm_nt(
    const u16* __restrict__ A, const u16* __restrict__ B,
    const float* __restrict__ bias, const float* __restrict__ resid,
    void* __restrict__ Cout, int M, int Nn, int K)
{
  constexpr int BM = 128, BN = 128, BK = 32;
  __shared__ __align__(16) u16 As[BM * BK];
  __shared__ __align__(16) u16 Bs[BN * BK];
  const int tid = threadIdx.x;
  const int lane = tid & 63;
  const int wave = tid >> 6;
  const int m0 = blockIdx.y * BM;
  const int n0 = blockIdx.x * BN;
  const int wm = (wave >> 1) * 64;
  const int wn = (wave & 1) * 64;
  const int fr = lane & 15;   // fragment m/n index
  const int fq = lane >> 4;   // quad -> k-group / row-group
  const int srow = lane >> 2;            // staging: 4 lanes per 64 B row
  const int skoff = (lane & 3) * 8;      // shorts within row

  f32x4 acc[4][4];
#pragma unroll
  for (int i = 0; i < 4; ++i)
#pragma unroll
    for (int j = 0; j < 4; ++j) acc[i][j] = 0.f;

  for (int k0 = 0; k0 < K; k0 += BK) {
    __syncthreads();
#pragma unroll
    for (int r = 0; r < 2; ++r) {
      const int rowbase = r * 64 + wave * 16;        // wave-uniform
      gload16(A + (size_t)(m0 + rowbase + srow) * K + k0 + skoff, As + rowbase * BK);
      gload16(B + (size_t)(n0 + rowbase + srow) * K + k0 + skoff, Bs + rowbase * BK);
    }
    __syncthreads();
    bf16x8 af[4], bfr[4];
#pragma unroll
    for (int mi = 0; mi < 4; ++mi)
      af[mi] = *(const bf16x8*)(As + (wm + mi * 16 + fr) * BK + fq * 8);
#pragma unroll
    for (int ni = 0; ni < 4; ++ni)
      bfr[ni] = *(const bf16x8*)(Bs + (wn + ni * 16 + fr) * BK + fq * 8);
#pragma unroll
    for (int mi = 0; mi < 4; ++mi)
#pragma unroll
      for (int ni = 0; ni < 4; ++ni)
        acc[mi][ni] = __builtin_amdgcn_mfma_f32_16x16x32_bf16(af[mi], bfr[ni], acc[mi][ni], 0, 0, 0);
  }

#pragma unroll
  for (int mi = 0; mi < 4; ++mi) {
#pragma unroll
    for (int ni = 0; ni < 4; ++ni) {
      const int col = n0 + wn + ni * 16 + fr;
      const float bv = bias[col];
#pragma unroll
      for (int rr = 0; rr < 4; ++rr) {
        const int row = m0 + wm + mi * 16 + fq * 4 + rr;   // C/D: row=quad*4+reg, col=lane&15
        float v = acc[mi][ni][rr] + bv;
        if (EPI == 1) {
          // gelu_tanh(v) == v * sigmoid(2u), u = 0.79788456*(v+0.044715 v^3)
          const float nu = -1.5957691216057308f * (v + 0.044715f * v * v * v);
          const float sg = __builtin_amdgcn_rcpf(1.f + __expf(nu));
          ((u16*)Cout)[(size_t)row * Nn + col] = f2bf(v * sg);
        } else if (EPI == 2) {
          ((float*)Cout)[(size_t)row * Nn + col] = v + resid[(size_t)row * Nn + col];
        } else {
          const int pk = __builtin_amdgcn_cvt_pk_fp8_f32(v, v, 0, false);
          ((unsigned char*)Cout)[(size_t)row * Nn + col] = (unsigned char)(pk & 0xFF);
        }
      }
    }
  }
}

// ---------------------------------------------------------------- edge pass
// 8 edges per wave; lane = (edge_in_group, head): eg=lane>>3, h=lane&7.
// Each lane owns a full 64-dim head dot (fp8 decode in-lane, no shuffles).
// No segment-max: logits bounded (~|8|), exp safe in fp32; softmax shift-invariant.
__global__ __launch_bounds__(256) void edge_kernel(
    const unsigned char* __restrict__ qk8, const float* __restrict__ att_bias,
    const float* __restrict__ dist, const float* __restrict__ src_pos,
    const int* __restrict__ row_index, const int* __restrict__ src_index,
    const int* __restrict__ org_to_src,
    float* __restrict__ den, float* __restrict__ wsum, float* __restrict__ wsp)
{
  const int lane = threadIdx.x & 63;
  const int wave = threadIdx.x >> 6;
  const int eg = lane >> 3;
  const int h  = lane & 7;
  const int e  = blockIdx.x * 32 + wave * 8 + eg;
  const int row = row_index[e];
  const int s   = src_index[e];
  const int kr  = org_to_src[s];
  const unsigned char* qp = qk8 + (size_t)row * 1024 + h * 64;
  const unsigned char* kp = qk8 + (size_t)kr * 1024 + 512 + h * 64;
  unsigned int q[16], k[16];
  *(uint4*)(q + 0)  = *(const uint4*)(qp);
  *(uint4*)(q + 4)  = *(const uint4*)(qp + 16);
  *(uint4*)(q + 8)  = *(const uint4*)(qp + 32);
  *(uint4*)(q + 12) = *(const uint4*)(qp + 48);
  *(uint4*)(k + 0)  = *(const uint4*)(kp);
  *(uint4*)(k + 4)  = *(const uint4*)(kp + 16);
  *(uint4*)(k + 8)  = *(const uint4*)(kp + 32);
  *(uint4*)(k + 12) = *(const uint4*)(kp + 48);
  float p = 0.f;
#pragma unroll
  for (int i = 0; i < 16; ++i) {
    const f32x2 ql = __builtin_amdgcn_cvt_pk_f32_fp8(q[i], false);
    const f32x2 qh = __builtin_amdgcn_cvt_pk_f32_fp8(q[i], true);
    const f32x2 kl = __builtin_amdgcn_cvt_pk_f32_fp8(k[i], false);
    const f32x2 kh = __builtin_amdgcn_cvt_pk_f32_fp8(k[i], true);
    p = fmaf(ql.x, kl.x, p);
    p = fmaf(ql.y, kl.y, p);
    p = fmaf(qh.x, kh.x, p);
    p = fmaf(qh.y, kh.y, p);
  }
  const float logit = p * 0.125f + att_bias[(size_t)h * E_EDGES + e];
  const float pe = __expf(logit);
  const float dv = dist[e];
  const float w = (dv == 0.f) ? 0.f : pe / dv;
  const int idx = row * 8 + h;
  atomicAdd(&den[idx], pe);
  atomicAdd(&wsum[idx], w);
  atomicAdd(&wsp[idx * 3 + 0], w * src_pos[(size_t)s * 3 + 0]);
  atomicAdd(&wsp[idx * 3 + 1], w * src_pos[(size_t)s * 3 + 1]);
  atomicAdd(&wsp[idx * 3 + 2], w * src_pos[(size_t)s * 3 + 2]);
}

// ---------------------------------------------------------------- feat assembly
__global__ __launch_bounds__(256) void feat_kernel(
    const float* __restrict__ den, const float* __restrict__ wsum,
    const float* __restrict__ wsp, const float* __restrict__ pos,
    u16* __restrict__ zcat)
{
  const int t = blockIdx.x * 256 + threadIdx.x;   // 0 .. N*H-1
  const int row = t >> 3, h = t & 7;
  const float d = den[t];
  const float invd = (d != 0.f) ? 1.f / d : 0.f;  // empty rows -> feat 0 (matches ref)
  const float rsum = wsum[t] * invd;
  u16* out = zcat + (size_t)row * KIN + D + h * 3;
#pragma unroll
  for (int c = 0; c < 3; ++c)
    out[c] = f2bf(wsp[t * 3 + c] * invd - rsum * pos[row * 3 + c]);
}

// ---------------------------------------------------------------- launch
extern "C" void kernel_launch(void* const* d_in, const int* in_sizes, int n_in,
                              void* d_out, int out_size, void* d_ws, size_t ws_size,
                              hipStream_t stream)
{
  const float* x        = (const float*)d_in[0];
  const float* Wq       = (const float*)d_in[1];
  const float* bq       = (const float*)d_in[2];
  const float* Wk       = (const float*)d_in[3];
  const float* bk       = (const float*)d_in[4];
  const float* g_att    = (const float*)d_in[5];
  const float* b_att    = (const float*)d_in[6];
  const float* g_mlp    = (const float*)d_in[7];
  const float* b_mlp    = (const float*)d_in[8];
  const float* W_in     = (const float*)d_in[9];
  const float* b_in     = (const float*)d_in[10];
  const float* W_out    = (const float*)d_in[11];
  const float* b_out    = (const float*)d_in[12];
  const float* att_bias = (const float*)d_in[13];
  const float* dist     = (const float*)d_in[14];
  const float* pos      = (const float*)d_in[15];
  const float* src_pos  = (const float*)d_in[16];
  const int* row_index  = (const int*)d_in[17];
  const int* src_index  = (const int*)d_in[18];
  const int* org_to_src = (const int*)d_in[19];

  char* ws = (char*)d_ws;
  u16*   zatt = (u16*)(ws + OFF_ZATT);
  u16*   zcat = (u16*)(ws + OFF_ZCAT);
  u16*   wqk  = (u16*)(ws + OFF_WQK);
  float* bqk  = (float*)(ws + OFF_BQK);
  u16*   win  = (u16*)(ws + OFF_WIN);
  u16*   wout = (u16*)(ws + OFF_WOUT);
  unsigned char* qk8 = (unsigned char*)(ws + OFF_QK);
  float* den  = (float*)(ws + OFF_DEN);
  float* wsum = (float*)(ws + OFF_WSUM);
  float* wsp  = (float*)(ws + OFF_WSP);
  u16*   hbf  = (u16*)(ws + OFF_HBF);

  // den+wsum+wsp are contiguous: one async memset (ws is poisoned each call)
  hipMemsetAsync(ws + OFF_DEN, 0, 2621440, stream);

  prep_weights<<<2176, 256, 0, stream>>>(Wq, Wk, bq, bk, W_in, W_out, wqk, bqk, win, wout);
  ln_kernel<<<N_NODES, 256, 0, stream>>>(x, g_att, b_att, g_mlp, b_mlp, zatt, zcat);
  gemm_nt<4><<<dim3(8, 128), 256, 0, stream>>>(zatt, wqk, bqk, nullptr, qk8, N_NODES, 1024, 512);
  edge_kernel<<<E_EDGES / 32, 256, 0, stream>>>(qk8, att_bias, dist, src_pos,
                                                row_index, src_index, org_to_src, den, wsum, wsp);
  feat_kernel<<<512, 256, 0, stream>>>(den, wsum, wsp, pos, zcat);
  gemm_nt<1><<<dim3(8, 128), 256, 0, stream>>>(zcat, win, b_in, nullptr, hbf, N_NODES, 1024, KIN);
  gemm_nt<2><<<dim3(4, 128), 256, 0, stream>>>(hbf, wout, b_out, x, d_out, N_NODES, 512, 1024);
}

// Round 4
// 337.570 us; speedup vs baseline: 1.0788x; 1.0788x over previous
//
#include <hip/hip_runtime.h>
#include <math.h>

// PositionFeaturizer on MI355X — round 3:
//  * edge_kernel: back to coalesced layout (2 edges/wave, 32 lanes sweep the
//    512 B fp8 row in one instruction) + distributed atomics (R2 regression fix)
//  * GEMM grid transposed: blockIdx.x = row-panel -> XCD gets a fixed set of
//    A row-panels (2-4 MB, L2-resident) instead of streaming all of A per XCD

typedef unsigned short u16;
typedef __attribute__((ext_vector_type(8))) short bf16x8;   // 8 bf16 in 4 VGPRs
typedef __attribute__((ext_vector_type(4))) float f32x4;
typedef __attribute__((ext_vector_type(2))) float f32x2;

constexpr int N_NODES = 16384;
constexpr int E_EDGES = 262144;
constexpr int D = 512;
constexpr int KIN = 544;    // 536 padded to multiple of 32

// workspace layout (bytes)
constexpr size_t OFF_ZATT = 0;                       // 16384*512*2  = 16,777,216
constexpr size_t OFF_ZCAT = 16777216;                // 16384*544*2  = 17,825,792
constexpr size_t OFF_WQK  = 34603008;                // 1024*512*2   = 1,048,576
constexpr size_t OFF_BQK  = 35651584;                // 1024*4       = 4,096
constexpr size_t OFF_WIN  = 35655680;                // 1024*544*2   = 1,114,112
constexpr size_t OFF_WOUT = 36769792;                // 512*1024*2   = 1,048,576
constexpr size_t OFF_QK   = 37818368;                // 16384*1024*1 = 16,777,216 (fp8)
constexpr size_t OFF_DEN  = 104927232;               // 16384*8*4    = 524,288
constexpr size_t OFF_WSUM = 105451520;               // 524,288
constexpr size_t OFF_WSP  = 105975808;               // 16384*8*3*4  = 1,572,864
constexpr size_t OFF_HBF  = 107548672;               // 16384*1024*2 = 33,554,432

static __device__ __forceinline__ u16 f2bf(float f) {
  union { float f; unsigned int u; } v; v.f = f;
  unsigned int u = v.u;
  u = u + 0x7FFFu + ((u >> 16) & 1u);   // RNE
  return (u16)(u >> 16);
}
// async global->LDS, 16 B per lane; LDS dest = wave-uniform base + lane*16
static __device__ __forceinline__ void gload16(const u16* g, u16* l) {
  __builtin_amdgcn_global_load_lds(
      (const __attribute__((address_space(1))) unsigned int*)g,
      (__attribute__((address_space(3))) unsigned int*)l, 16, 0, 0);
}

// ---------------------------------------------------------------- weights cast
__global__ __launch_bounds__(256) void prep_weights(
    const float* __restrict__ Wq, const float* __restrict__ Wk,
    const float* __restrict__ bq, const float* __restrict__ bk,
    const float* __restrict__ W_in, const float* __restrict__ W_out,
    u16* __restrict__ wqk, float* __restrict__ bqk,
    u16* __restrict__ win, u16* __restrict__ wout)
{
  const int gid = blockIdx.x * 256 + threadIdx.x;
  if (gid < 512 * 1024) {
    wqk[gid]  = f2bf(gid < 512 * 512 ? Wq[gid] : Wk[gid - 512 * 512]);
    wout[gid] = f2bf(W_out[gid]);
  }
  if (gid < 1024 * 544) {
    const int r = gid / 544, c = gid - r * 544;
    win[gid] = f2bf(c < 536 ? W_in[r * 536 + c] : 0.f);
  }
  if (gid < 1024) bqk[gid] = gid < 512 ? bq[gid] : bk[gid - 512];
}

// ---------------------------------------------------------------- dual layernorm
__global__ __launch_bounds__(256) void ln_kernel(
    const float* __restrict__ x,
    const float* __restrict__ g1, const float* __restrict__ b1,
    const float* __restrict__ g2, const float* __restrict__ b2,
    u16* __restrict__ zatt, u16* __restrict__ zcat)
{
  const int row = blockIdx.x;
  const int t = threadIdx.x;
  const float2 v = *(const float2*)(x + (size_t)row * D + t * 2);
  float s = v.x + v.y;
  float s2 = v.x * v.x + v.y * v.y;
#pragma unroll
  for (int m = 1; m < 64; m <<= 1) {
    s  += __shfl_xor(s, m, 64);
    s2 += __shfl_xor(s2, m, 64);
  }
  __shared__ float red[8];
  const int wv = t >> 6;
  if ((t & 63) == 0) { red[wv] = s; red[4 + wv] = s2; }
  __syncthreads();
  s  = red[0] + red[1] + red[2] + red[3];
  s2 = red[4] + red[5] + red[6] + red[7];
  const float mu = s * (1.f / D);
  const float var = s2 * (1.f / D) - mu * mu;
  const float rs = rsqrtf(var + 1e-5f);
  const int c0 = t * 2;
  const float n0 = (v.x - mu) * rs, n1 = (v.y - mu) * rs;
  zatt[(size_t)row * D + c0]       = f2bf(n0 * g1[c0] + b1[c0]);
  zatt[(size_t)row * D + c0 + 1]   = f2bf(n1 * g1[c0 + 1] + b1[c0 + 1]);
  zcat[(size_t)row * KIN + c0]     = f2bf(n0 * g2[c0] + b2[c0]);
  zcat[(size_t)row * KIN + c0 + 1] = f2bf(n1 * g2[c0 + 1] + b2[c0 + 1]);
  if (t < 32) zcat[(size_t)row * KIN + D + t] = 0;   // feat slot + K-pad zeroed
}

// ---------------------------------------------------------------- NT GEMM (bf16 MFMA)
// C[M,Nn] = A[M,K] @ B[Nn,K]^T + bias.
// EPI: 1=fast-gelu->bf16 out; 2=+resid f32 out; 4=fp8 e4m3 out.
// Grid: blockIdx.x = M row-panel (fast -> XCD id), blockIdx.y = N column.
template <int EPI>
__global__ __launch_bounds__(256) void gemm_nt(
    const u16* __restrict__ A, const u16* __restrict__ B,
    const float* __restrict__ bias, const float* __restrict__ resid,
    void* __restrict__ Cout, int M, int Nn, int K)
{
  constexpr int BM = 128, BN = 128, BK = 32;
  __shared__ __align__(16) u16 As[BM * BK];
  __shared__ __align__(16) u16 Bs[BN * BK];
  const int tid = threadIdx.x;
  const int lane = tid & 63;
  const int wave = tid >> 6;
  const int m0 = blockIdx.x * BM;    // row-panel on x: per-XCD L2-resident A
  const int n0 = blockIdx.y * BN;
  const int wm = (wave >> 1) * 64;
  const int wn = (wave & 1) * 64;
  const int fr = lane & 15;   // fragment m/n index
  const int fq = lane >> 4;   // quad -> k-group / row-group
  const int srow = lane >> 2;            // staging: 4 lanes per 64 B row
  const int skoff = (lane & 3) * 8;      // shorts within row

  f32x4 acc[4][4];
#pragma unroll
  for (int i = 0; i < 4; ++i)
#pragma unroll
    for (int j = 0; j < 4; ++j) acc[i][j] = 0.f;

  for (int k0 = 0; k0 < K; k0 += BK) {
    __syncthreads();
#pragma unroll
    for (int r = 0; r < 2; ++r) {
      const int rowbase = r * 64 + wave * 16;        // wave-uniform
      gload16(A + (size_t)(m0 + rowbase + srow) * K + k0 + skoff, As + rowbase * BK);
      gload16(B + (size_t)(n0 + rowbase + srow) * K + k0 + skoff, Bs + rowbase * BK);
    }
    __syncthreads();
    bf16x8 af[4], bfr[4];
#pragma unroll
    for (int mi = 0; mi < 4; ++mi)
      af[mi] = *(const bf16x8*)(As + (wm + mi * 16 + fr) * BK + fq * 8);
#pragma unroll
    for (int ni = 0; ni < 4; ++ni)
      bfr[ni] = *(const bf16x8*)(Bs + (wn + ni * 16 + fr) * BK + fq * 8);
#pragma unroll
    for (int mi = 0; mi < 4; ++mi)
#pragma unroll
      for (int ni = 0; ni < 4; ++ni)
        acc[mi][ni] = __builtin_amdgcn_mfma_f32_16x16x32_bf16(af[mi], bfr[ni], acc[mi][ni], 0, 0, 0);
  }

#pragma unroll
  for (int mi = 0; mi < 4; ++mi) {
#pragma unroll
    for (int ni = 0; ni < 4; ++ni) {
      const int col = n0 + wn + ni * 16 + fr;
      const float bv = bias[col];
#pragma unroll
      for (int rr = 0; rr < 4; ++rr) {
        const int row = m0 + wm + mi * 16 + fq * 4 + rr;   // C/D: row=quad*4+reg, col=lane&15
        float v = acc[mi][ni][rr] + bv;
        if (EPI == 1) {
          // gelu_tanh(v) == v * sigmoid(2u), u = 0.79788456*(v+0.044715 v^3)
          const float nu = -1.5957691216057308f * (v + 0.044715f * v * v * v);
          const float sg = __builtin_amdgcn_rcpf(1.f + __expf(nu));
          ((u16*)Cout)[(size_t)row * Nn + col] = f2bf(v * sg);
        } else if (EPI == 2) {
          ((float*)Cout)[(size_t)row * Nn + col] = v + resid[(size_t)row * Nn + col];
        } else {
          const int pk = __builtin_amdgcn_cvt_pk_fp8_f32(v, v, 0, false);
          ((unsigned char*)Cout)[(size_t)row * Nn + col] = (unsigned char)(pk & 0xFF);
        }
      }
    }
  }
}

// ---------------------------------------------------------------- edge pass
// 2 edges per wave, 32 lanes per edge; lane sub: h=sub>>2 (head), j=sub&3.
// Each lane reads 16 B (16 fp8) -> 32-lane group sweeps the full 512 B row in
// ONE coalesced instruction. Shuffle-reduce over j; atomics spread over j lanes.
// No segment-max: logits bounded (~|8|), exp safe in fp32; softmax shift-invariant.
__global__ __launch_bounds__(256) void edge_kernel(
    const unsigned char* __restrict__ qk8, const float* __restrict__ att_bias,
    const float* __restrict__ dist, const float* __restrict__ src_pos,
    const int* __restrict__ row_index, const int* __restrict__ src_index,
    const int* __restrict__ org_to_src,
    float* __restrict__ den, float* __restrict__ wsum, float* __restrict__ wsp)
{
  const int lane = threadIdx.x & 63;
  const int wave = threadIdx.x >> 6;
  const int e = blockIdx.x * 8 + wave * 2 + (lane >> 5);
  const int sub = lane & 31;
  const int h = sub >> 2, j = sub & 3;
  const int row = row_index[e];
  const int s = src_index[e];
  const int kr = org_to_src[s];
  const unsigned char* qp = qk8 + (size_t)row * 1024 + sub * 16;
  const unsigned char* kp = qk8 + (size_t)kr * 1024 + 512 + sub * 16;
  const uint4 q = *(const uint4*)qp;        // 16 fp8 = this lane's j-th 16-dim chunk of head h
  const uint4 k = *(const uint4*)kp;
  float p = 0.f;
  {
    const unsigned int* qu = (const unsigned int*)&q;
    const unsigned int* ku = (const unsigned int*)&k;
#pragma unroll
    for (int i = 0; i < 4; ++i) {
      const f32x2 ql = __builtin_amdgcn_cvt_pk_f32_fp8(qu[i], false);
      const f32x2 qh = __builtin_amdgcn_cvt_pk_f32_fp8(qu[i], true);
      const f32x2 kl = __builtin_amdgcn_cvt_pk_f32_fp8(ku[i], false);
      const f32x2 kh = __builtin_amdgcn_cvt_pk_f32_fp8(ku[i], true);
      p = fmaf(ql.x, kl.x, p);
      p = fmaf(ql.y, kl.y, p);
      p = fmaf(qh.x, kh.x, p);
      p = fmaf(qh.y, kh.y, p);
    }
  }
  p += __shfl_xor(p, 1, 64);
  p += __shfl_xor(p, 2, 64);                     // all 4 j-lanes of head group hold the dot
  const float logit = p * 0.125f + att_bias[(size_t)h * E_EDGES + e];
  const float pe = __expf(logit);
  const float dv = dist[e];
  const float inv = (dv == 0.f) ? 0.f : 1.f / dv;
  const float w = pe * inv;
  const int idx = row * 8 + h;
  if (j == 0) {
    atomicAdd(&den[idx], pe);
  } else if (j == 1) {
    atomicAdd(&wsum[idx], w);
    atomicAdd(&wsp[idx * 3 + 2], w * src_pos[(size_t)s * 3 + 2]);
  } else {
    atomicAdd(&wsp[idx * 3 + (j - 2)], w * src_pos[(size_t)s * 3 + (j - 2)]);
  }
}

// ---------------------------------------------------------------- feat assembly
__global__ __launch_bounds__(256) void feat_kernel(
    const float* __restrict__ den, const float* __restrict__ wsum,
    const float* __restrict__ wsp, const float* __restrict__ pos,
    u16* __restrict__ zcat)
{
  const int t = blockIdx.x * 256 + threadIdx.x;   // 0 .. N*H-1
  const int row = t >> 3, h = t & 7;
  const float d = den[t];
  const float invd = (d != 0.f) ? 1.f / d : 0.f;  // empty rows -> feat 0 (matches ref)
  const float rsum = wsum[t] * invd;
  u16* out = zcat + (size_t)row * KIN + D + h * 3;
#pragma unroll
  for (int c = 0; c < 3; ++c)
    out[c] = f2bf(wsp[t * 3 + c] * invd - rsum * pos[row * 3 + c]);
}

// ---------------------------------------------------------------- launch
extern "C" void kernel_launch(void* const* d_in, const int* in_sizes, int n_in,
                              void* d_out, int out_size, void* d_ws, size_t ws_size,
                              hipStream_t stream)
{
  const float* x        = (const float*)d_in[0];
  const float* Wq       = (const float*)d_in[1];
  const float* bq       = (const float*)d_in[2];
  const float* Wk       = (const float*)d_in[3];
  const float* bk       = (const float*)d_in[4];
  const float* g_att    = (const float*)d_in[5];
  const float* b_att    = (const float*)d_in[6];
  const float* g_mlp    = (const float*)d_in[7];
  const float* b_mlp    = (const float*)d_in[8];
  const float* W_in     = (const float*)d_in[9];
  const float* b_in     = (const float*)d_in[10];
  const float* W_out    = (const float*)d_in[11];
  const float* b_out    = (const float*)d_in[12];
  const float* att_bias = (const float*)d_in[13];
  const float* dist     = (const float*)d_in[14];
  const float* pos      = (const float*)d_in[15];
  const float* src_pos  = (const float*)d_in[16];
  const int* row_index  = (const int*)d_in[17];
  const int* src_index  = (const int*)d_in[18];
  const int* org_to_src = (const int*)d_in[19];

  char* ws = (char*)d_ws;
  u16*   zatt = (u16*)(ws + OFF_ZATT);
  u16*   zcat = (u16*)(ws + OFF_ZCAT);
  u16*   wqk  = (u16*)(ws + OFF_WQK);
  float* bqk  = (float*)(ws + OFF_BQK);
  u16*   win  = (u16*)(ws + OFF_WIN);
  u16*   wout = (u16*)(ws + OFF_WOUT);
  unsigned char* qk8 = (unsigned char*)(ws + OFF_QK);
  float* den  = (float*)(ws + OFF_DEN);
  float* wsum = (float*)(ws + OFF_WSUM);
  float* wsp  = (float*)(ws + OFF_WSP);
  u16*   hbf  = (u16*)(ws + OFF_HBF);

  // den+wsum+wsp are contiguous: one async memset (ws is poisoned each call)
  hipMemsetAsync(ws + OFF_DEN, 0, 2621440, stream);

  prep_weights<<<2176, 256, 0, stream>>>(Wq, Wk, bq, bk, W_in, W_out, wqk, bqk, win, wout);
  ln_kernel<<<N_NODES, 256, 0, stream>>>(x, g_att, b_att, g_mlp, b_mlp, zatt, zcat);
  gemm_nt<4><<<dim3(128, 8), 256, 0, stream>>>(zatt, wqk, bqk, nullptr, qk8, N_NODES, 1024, 512);
  edge_kernel<<<E_EDGES / 8, 256, 0, stream>>>(qk8, att_bias, dist, src_pos,
                                               row_index, src_index, org_to_src, den, wsum, wsp);
  feat_kernel<<<512, 256, 0, stream>>>(den, wsum, wsp, pos, zcat);
  gemm_nt<1><<<dim3(128, 8), 256, 0, stream>>>(zcat, win, b_in, nullptr, hbf, N_NODES, 1024, KIN);
  gemm_nt<2><<<dim3(128, 4), 256, 0, stream>>>(hbf, wout, b_out, x, d_out, N_NODES, 512, 1024);
}